// Round 4
// baseline (4345.946 us; speedup 1.0000x reference)
//
#include <hip/hip_runtime.h>
#include <hip/hip_bf16.h>

using bf16 = __hip_bfloat16;
typedef short short8 __attribute__((ext_vector_type(8)));
typedef short short4v __attribute__((ext_vector_type(4)));
typedef float floatx4 __attribute__((ext_vector_type(4)));

#define B_   16
#define C_   768
#define NP_  196
#define H_   12
#define NPNP 38416   // 196*196

static __device__ __forceinline__ float b2f(bf16 v) { return __bfloat162float(v); }
static __device__ __forceinline__ float bits2f(unsigned short u) {
    union { unsigned int i; float f; } c; c.i = ((unsigned int)u) << 16; return c.f;
}
static __device__ __forceinline__ unsigned short f2bfbits(float f) {
    bf16 t = __float2bfloat16(f);
    return *(unsigned short*)&t;
}

// Fused "drain LDS ops + barrier" in ONE asm with memory clobber: no memory
// op can be reordered across it (raw __builtin s_barrier is IntrNoMem in
// LLVM and does NOT fence memory). vmcnt is intentionally NOT drained.
#define LDS_BARRIER() asm volatile("s_waitcnt lgkmcnt(0)\n\ts_barrier" ::: "memory")

// ---------------------------------------------------------------------------
// Batched MFMA GEMM:  C[z][m][n] = act( scale * sum_k A[z][m][k]*W[z][n][k] + bias[n] )
// A bf16 row-major. W bf16 (WFP=0) or fp32 (WFP=1, converted while staging).
// K multiple of 32 (>=64 per slice), lda/ldw multiple of 8.
// Batch offsets two-level for A, W, C:  off = (z/BI)*so + (z%BI)*si.
// ksplit: blockIdx.z = z*ksplit + ks; slice ks covers K/ksplit; when ksplit>1
// the resg epilogue uses atomicAdd and bias applies only on slice 0.
// swz: bijective 8-XCD chunked remap of the (x,y) grid for L2 locality.
// Pipeline: LDS double-buffer + DEPTH-2 register prefetch; fused
// lgkmcnt(0)+s_barrier keeps global loads in flight across barriers.
// ---------------------------------------------------------------------------
template<int BM, int BN, int WM, int WN, int WFP>
__global__ __launch_bounds__(256)
void k_mgemm(const bf16* __restrict__ A, long long sAo, long long sAi, int ABI, int lda,
             const void* __restrict__ W, long long sWo, long long sWi, int WBI, int ldw,
             char* __restrict__ Cb, long long sCo, long long sCi, int CBI, int ldc,
             const float* __restrict__ bias, const float* __restrict__ resg,
             int M, int N, int K, float scale, int act, int outbf,
             int ksplit, int swz)
{
    constexpr int FM = BM / (16 * WM);
    constexpr int FN = BN / (16 * WN);
    constexpr int ACH = (BM * 4 + 255) / 256;
    constexpr int WCH = (BN * 4 + 255) / 256;

    __shared__ unsigned short As[2 * BM * 40];  // row stride 40 elems (80B)
    __shared__ unsigned short Ws[2 * BN * 40];

    int bx = blockIdx.x, by = blockIdx.y;
    if (swz) {
        int nx = gridDim.x, ny = gridDim.y;
        int nwg = nx * ny;
        int lin = by * nx + bx;
        int qq = nwg >> 3, rr = nwg & 7;
        int xcd = lin & 7, idx2 = lin >> 3;
        int s = (xcd < rr) ? (xcd * (qq + 1) + idx2)
                           : (rr * (qq + 1) + (xcd - rr) * qq + idx2);
        bx = s % nx; by = s / nx;
    }

    const int zz = blockIdx.z;
    const int z = zz / ksplit, ks = zz % ksplit;
    const int Ks = K / ksplit;
    const int kbeg = ks * Ks, kend = kbeg + Ks;

    const long long aoff = (long long)(z / ABI) * sAo + (long long)(z % ABI) * sAi;
    const long long woff = (long long)(z / WBI) * sWo + (long long)(z % WBI) * sWi;
    const unsigned short* Ag = (const unsigned short*)A + aoff;

    const int tid = threadIdx.x;
    const int lane = tid & 63, w = tid >> 6;
    const int wm = w / WN, wn = w % WN;
    const int p = lane & 15, q = lane >> 4;
    const int bm = by * BM, bn = bx * BN;

    short8  aR0[ACH], aR1[ACH];
    short8  wR0[WCH], wR1[WCH];
    floatx4 w0R0[WCH], w1R0[WCH], w0R1[WCH], w1R1[WCH];

#define LOADAB(aR, wR, w0R, w1R, K0_) do {                                       \
    _Pragma("unroll")                                                            \
    for (int i = 0; i < ACH; i++) {                                              \
        int c = tid + 256 * i;                                                   \
        if (c < BM * 4) {                                                        \
            int r = c >> 2, off = (c & 3) * 8;                                   \
            int am = bm + r; am = (am < M) ? am : (M - 1);                       \
            aR[i] = *(const short8*)(Ag + (size_t)am * lda + (K0_) + off);       \
        }                                                                        \
    }                                                                            \
    _Pragma("unroll")                                                            \
    for (int i = 0; i < WCH; i++) {                                              \
        int c = tid + 256 * i;                                                   \
        if (c < BN * 4) {                                                        \
            int r = c >> 2, off = (c & 3) * 8;                                   \
            int wr = bn + r; wr = (wr < N) ? wr : (N - 1);                       \
            if constexpr (WFP) {                                                 \
                const float* wp = (const float*)W + woff + (size_t)wr * ldw + (K0_) + off; \
                w0R[i] = *(const floatx4*)wp;                                    \
                w1R[i] = *(const floatx4*)(wp + 4);                              \
            } else {                                                             \
                wR[i] = *(const short8*)((const unsigned short*)W + woff         \
                         + (size_t)wr * ldw + (K0_) + off);                      \
            }                                                                    \
        }                                                                        \
    }                                                                            \
} while (0)

#define STORELDS(aR, wR, w0R, w1R, BUF_) do {                                    \
    unsigned short* Ab_ = As + (BUF_) * (BM * 40);                               \
    unsigned short* Wb_ = Ws + (BUF_) * (BN * 40);                               \
    _Pragma("unroll")                                                            \
    for (int i = 0; i < ACH; i++) {                                              \
        int c = tid + 256 * i;                                                   \
        if (c < BM * 4) {                                                        \
            int r = c >> 2, off = (c & 3) * 8;                                   \
            *(short8*)(&Ab_[r * 40 + off]) = aR[i];                              \
        }                                                                        \
    }                                                                            \
    _Pragma("unroll")                                                            \
    for (int i = 0; i < WCH; i++) {                                              \
        int c = tid + 256 * i;                                                   \
        if (c < BN * 4) {                                                        \
            int r = c >> 2, off = (c & 3) * 8;                                   \
            if constexpr (WFP) {                                                 \
                unsigned short* d = &Wb_[r * 40 + off];                          \
                _Pragma("unroll")                                                \
                for (int j = 0; j < 4; j++) d[j]     = f2bfbits(w0R[i][j]);      \
                _Pragma("unroll")                                                \
                for (int j = 0; j < 4; j++) d[4 + j] = f2bfbits(w1R[i][j]);      \
            } else {                                                             \
                *(short8*)(&Wb_[r * 40 + off]) = wR[i];                          \
            }                                                                    \
        }                                                                        \
    }                                                                            \
} while (0)

    floatx4 acc[FM][FN] = {};

    auto compute = [&](int cc) {
        const unsigned short* Ab = As + cc * (BM * 40);
        const unsigned short* Wb = Ws + cc * (BN * 40);
        short8 af[FM], wf[FN];
#pragma unroll
        for (int i = 0; i < FM; i++)
            af[i] = *(const short8*)(&Ab[(wm * (BM / WM) + i * 16 + p) * 40 + q * 8]);
#pragma unroll
        for (int j = 0; j < FN; j++)
            wf[j] = *(const short8*)(&Wb[(wn * (BN / WN) + j * 16 + p) * 40 + q * 8]);
        __builtin_amdgcn_s_setprio(1);
#pragma unroll
        for (int i = 0; i < FM; i++)
#pragma unroll
            for (int j = 0; j < FN; j++)
                acc[i][j] = __builtin_amdgcn_mfma_f32_16x16x32_bf16(af[i], wf[j], acc[i][j], 0, 0, 0);
        __builtin_amdgcn_s_setprio(0);
    };

    // prologue: k0 -> LDS0; k1 -> rb0; k2 -> rb1  (depth-2 steady state)
    LOADAB(aR0, wR0, w0R0, w1R0, kbeg);
    STORELDS(aR0, wR0, w0R0, w1R0, 0);
    if (kbeg + 32 < kend) LOADAB(aR0, wR0, w0R0, w1R0, kbeg + 32);
    if (kbeg + 64 < kend) LOADAB(aR1, wR1, w0R1, w1R1, kbeg + 64);
    LDS_BARRIER();

    int cur = 0;
    for (int k0 = kbeg; k0 < kend; k0 += 64) {
        // step A (even): consumes LDS[cur], stores rb0 (k0+32)
        compute(cur);
        if (k0 + 32 < kend) {
            STORELDS(aR0, wR0, w0R0, w1R0, cur ^ 1);
            if (k0 + 96 < kend) LOADAB(aR0, wR0, w0R0, w1R0, k0 + 96);
            LDS_BARRIER();
        }
        cur ^= 1;
        // step B (odd): consumes LDS[cur], stores rb1 (k0+64)
        if (k0 + 32 < kend) {
            compute(cur);
            if (k0 + 64 < kend) {
                STORELDS(aR1, wR1, w0R1, w1R1, cur ^ 1);
                if (k0 + 128 < kend) LOADAB(aR1, wR1, w0R1, w1R1, k0 + 128);
                LDS_BARRIER();
            }
            cur ^= 1;
        }
    }
#undef LOADAB
#undef STORELDS

    const long long coff = (long long)(z / CBI) * sCo + (long long)(z % CBI) * sCi;
    float* Cf = (float*)Cb + coff;
    bf16*  Ch = (bf16*)Cb + coff;
#pragma unroll
    for (int i = 0; i < FM; i++) {
#pragma unroll
        for (int r = 0; r < 4; r++) {
            int gm = bm + wm * (BM / WM) + i * 16 + q * 4 + r;
            if (gm >= M) continue;
#pragma unroll
            for (int j = 0; j < FN; j++) {
                int gn = bn + wn * (BN / WN) + j * 16 + p;
                if (gn >= N) continue;
                float v = acc[i][j][r] * scale;
                if (bias && ks == 0) v += bias[gn];
                if (act) v = 0.5f * v * (1.0f + erff(v * 0.70710678118654752f));
                if (resg) {
                    float av = resg[gn] * v;
                    if (ksplit > 1) atomicAdd(&Cf[(size_t)gm * ldc + gn], av);
                    else            Cf[(size_t)gm * ldc + gn] += av;
                } else if (outbf) Ch[(size_t)gm * ldc + gn] = __float2bfloat16(v);
                else              Cf[(size_t)gm * ldc + gn] = v;
            }
        }
    }
}

// ---------------------------------------------------------------------------
// Skinny GEMM for M=16:  C[16][n] = act(scale * A[16xK] @ W[NxK]^T + bias[n])
// W fp32. 4 waves/block, each wave owns one output column n (full K, no
// atomics). A tile (16x256 bf16) staged in LDS per pass; W read coalesced
// float4 per lane. Shuffle-reduce 16 partial sums at the end. grid.x = N/4.
// ---------------------------------------------------------------------------
__global__ __launch_bounds__(256)
void k_skinny(const bf16* __restrict__ A, long long lda,
              const float* __restrict__ W, int ldw,
              char* __restrict__ Cb, int ldc,
              const float* __restrict__ bias, const float* __restrict__ resg,
              int N, int K, float scale, int act, int outbf)
{
    __shared__ unsigned short Asl[16 * 256];   // 8 KB
    const int t = threadIdx.x;
    const int wv = t >> 6, lane = t & 63;
    const int n = blockIdx.x * 4 + wv;

    float acc[16] = {};
    for (int p0 = 0; p0 < K; p0 += 256) {
        {   // stage A tile: row r = t>>4, 32B chunk (t&15)*16
            int r = t >> 4, c0 = (t & 15) * 16;
            const unsigned short* ap = (const unsigned short*)A + (size_t)r * lda + p0 + c0;
            *(short8*)(&Asl[r * 256 + c0])     = *(const short8*)ap;
            *(short8*)(&Asl[r * 256 + c0 + 8]) = *(const short8*)(ap + 8);
        }
        __syncthreads();
        floatx4 wvv = *(const floatx4*)(W + (size_t)n * ldw + p0 + lane * 4);
#pragma unroll
        for (int m = 0; m < 16; m++) {
            short4v av = *(const short4v*)(&Asl[m * 256 + lane * 4]);
            float s = acc[m];
            s += wvv[0] * bits2f((unsigned short)av[0]);
            s += wvv[1] * bits2f((unsigned short)av[1]);
            s += wvv[2] * bits2f((unsigned short)av[2]);
            s += wvv[3] * bits2f((unsigned short)av[3]);
            acc[m] = s;
        }
        __syncthreads();
    }
#pragma unroll
    for (int m = 0; m < 16; m++) {
        float s = acc[m];
#pragma unroll
        for (int off = 32; off > 0; off >>= 1) s += __shfl_down(s, off);
        acc[m] = s;
    }
    if (lane == 0) {
        float* Cf = (float*)Cb;
        bf16*  Ch = (bf16*)Cb;
        float bs = bias ? bias[n] : 0.f;
        float rg = resg ? resg[n] : 0.f;
#pragma unroll
        for (int m = 0; m < 16; m++) {
            float v = acc[m] * scale + bs;
            if (act) v = 0.5f * v * (1.0f + erff(v * 0.70710678118654752f));
            if (resg)       Cf[(size_t)m * ldc + n] += rg * v;
            else if (outbf) Ch[(size_t)m * ldc + n] = __float2bfloat16(v);
            else            Cf[(size_t)m * ldc + n] = v;
        }
    }
}

// ---------------------------------------------------------------------------
__global__ __launch_bounds__(256)
void k_patch_gather(const float* __restrict__ x, bf16* __restrict__ p)
{
    int idx = blockIdx.x * 256 + threadIdx.x;            // 2,408,448
    int k = idx % 768;
    int n = (idx / 768) % NP_;
    int b = idx / (768 * NP_);
    int c = k >> 8, r = k & 255;
    int py = r >> 4, px = r & 15;
    int gy = n / 14, gx = n % 14;
    p[idx] = __float2bfloat16(x[(((size_t)b * 3 + c) * 224 + gy * 16 + py) * 224 + gx * 16 + px]);
}

__global__ __launch_bounds__(256)
void k_addpos(float* __restrict__ h, const float* __restrict__ pos)
{
    int idx = blockIdx.x * 256 + threadIdx.x;            // 2,408,448
    h[idx] += pos[idx % (NP_ * C_)];
}

// LayerNorm over C=768: fp32 in -> bf16 out. One block per row.
__device__ __forceinline__ void ln_row(const float* __restrict__ x,
                                       const float* __restrict__ w,
                                       const float* __restrict__ b,
                                       bf16* __restrict__ y, int t,
                                       float* red, float* stat)
{
    float a0 = x[t], a1 = x[t + 256], a2 = x[t + 512];
    float s = a0 + a1 + a2;
#pragma unroll
    for (int off = 32; off > 0; off >>= 1) s += __shfl_down(s, off);
    if ((t & 63) == 0) red[t >> 6] = s;
    __syncthreads();
    if (t == 0) stat[0] = (red[0] + red[1] + red[2] + red[3]) * (1.f / 768.f);
    __syncthreads();
    float m = stat[0];
    float d0 = a0 - m, d1 = a1 - m, d2 = a2 - m;
    float s2 = d0 * d0 + d1 * d1 + d2 * d2;
#pragma unroll
    for (int off = 32; off > 0; off >>= 1) s2 += __shfl_down(s2, off);
    if ((t & 63) == 0) red[t >> 6] = s2;
    __syncthreads();
    if (t == 0) stat[1] = rsqrtf((red[0] + red[1] + red[2] + red[3]) * (1.f / 768.f) + 1e-6f);
    __syncthreads();
    float r = stat[1];
    y[t]       = __float2bfloat16(d0 * r * w[t]       + b[t]);
    y[t + 256] = __float2bfloat16(d1 * r * w[t + 256] + b[t + 256]);
    y[t + 512] = __float2bfloat16(d2 * r * w[t + 512] + b[t + 512]);
}

__global__ __launch_bounds__(256)
void k_ln(const float* __restrict__ X, const float* __restrict__ w,
          const float* __restrict__ b, bf16* __restrict__ Y)
{
    __shared__ float red[4];
    __shared__ float stat[2];
    int row = blockIdx.x;
    ln_row(X + (size_t)row * C_, w, b, Y + (size_t)row * C_, threadIdx.x, red, stat);
}

__global__ __launch_bounds__(256)
void k_ln_cat(const float* __restrict__ cls, const float* __restrict__ h,
              const float* __restrict__ w, const float* __restrict__ b,
              bf16* __restrict__ Y)
{
    __shared__ float red[4];
    __shared__ float stat[2];
    int row = blockIdx.x;
    int bb = row / 197, tkn = row % 197;
    const float* src = (tkn == 0) ? (cls + (size_t)bb * C_)
                                  : (h + ((size_t)bb * NP_ + (tkn - 1)) * C_);
    ln_row(src, w, b, Y + (size_t)row * C_, threadIdx.x, red, stat);
}

// qkv bf16 [3136x2304] -> Qb,Kb [z][196][64]; z = b*12+h  (keeps Q/K out of
// the S-aliased region: S overlaps qkvB, so S-GEMM must not read qkvB)
__global__ __launch_bounds__(256)
void k_splitqk(const bf16* __restrict__ qkv, bf16* __restrict__ Qb, bf16* __restrict__ Kb)
{
    int idx = blockIdx.x * 256 + threadIdx.x;            // 2,408,448
    int d = idx & 63;
    int rest = idx >> 6;
    int n = rest % NP_, zz = rest / NP_;
    int b = zz / H_, hh = zz % H_;
    size_t src = ((size_t)b * NP_ + n) * 2304 + hh * 64 + d;
    Qb[idx] = qkv[src];
    Kb[idx] = qkv[src + 768];
}

// V transposed: VT[z][d][m] (m padded 196->224 with 0)
__global__ __launch_bounds__(256)
void k_splitv(const bf16* __restrict__ qkv, bf16* __restrict__ VT)
{
    int idx = blockIdx.x * 256 + threadIdx.x;            // 2,752,512
    int m = idx % 224;
    int rest = idx / 224;
    int d = rest & 63, zz = rest >> 6;
    int b = zz / H_, hh = zz % H_;
    bf16 v = __float2bfloat16(0.f);
    if (m < NP_) v = qkv[((size_t)b * NP_ + m) * 2304 + 1536 + hh * 64 + d];
    VT[idx] = v;
}

// ---------------------------------------------------------------------------
// Fused pre-mix + softmax + post-mix (reads S once, writes P bf16 [z][196][224])
// One block per (b, n): 3136 blocks x 256 threads, thread = column m.
// ---------------------------------------------------------------------------
__global__ __launch_bounds__(256)
void k_attn_mix(const float* __restrict__ S, const float* __restrict__ plw,
                const float* __restrict__ plb, const float* __restrict__ pww,
                const float* __restrict__ pwb, bf16* __restrict__ P)
{
    __shared__ float wpre[144], wpost[144], bpre[12], bpost[12];
    __shared__ float red[4][12];
    int tid = threadIdx.x;
    if (tid < 144) { wpre[tid] = plw[tid]; wpost[tid] = pww[tid]; }
    if (tid < 12)  { bpre[tid] = plb[tid]; bpost[tid] = pwb[tid]; }
    __syncthreads();
    int b = blockIdx.x / NP_, n = blockIdx.x % NP_;
    int m = tid;
    bool on = (m < NP_);
    const float* p0 = S + ((size_t)b * H_ * NP_ + n) * NP_ + (on ? m : 0);
    float v[12];
#pragma unroll
    for (int h = 0; h < 12; h++) v[h] = p0[(size_t)h * NPNP];
    float s[12];
#pragma unroll
    for (int g = 0; g < 12; g++) {
        float a = bpre[g];
#pragma unroll
        for (int h = 0; h < 12; h++) a += wpre[g * 12 + h] * v[h];
        s[g] = on ? a : -1e30f;
    }
    int wv = tid >> 6, ln = tid & 63;
    float mx[12];
#pragma unroll
    for (int g = 0; g < 12; g++) {
        float x = s[g];
#pragma unroll
        for (int off = 32; off > 0; off >>= 1) x = fmaxf(x, __shfl_down(x, off));
        mx[g] = x;
    }
    if (ln == 0) {
#pragma unroll
        for (int g = 0; g < 12; g++) red[wv][g] = mx[g];
    }
    __syncthreads();
#pragma unroll
    for (int g = 0; g < 12; g++)
        mx[g] = fmaxf(fmaxf(red[0][g], red[1][g]), fmaxf(red[2][g], red[3][g]));
    __syncthreads();
    float e[12], sm[12];
#pragma unroll
    for (int g = 0; g < 12; g++) {
        e[g] = on ? expf(s[g] - mx[g]) : 0.f;
        float x = e[g];
#pragma unroll
        for (int off = 32; off > 0; off >>= 1) x += __shfl_down(x, off);
        sm[g] = x;
    }
    if (ln == 0) {
#pragma unroll
        for (int g = 0; g < 12; g++) red[wv][g] = sm[g];
    }
    __syncthreads();
#pragma unroll
    for (int g = 0; g < 12; g++) {
        float tt = (red[0][g] + red[1][g]) + (red[2][g] + red[3][g]);
        e[g] *= 1.0f / tt;
    }
    if (on) {
        size_t base = ((size_t)b * H_ * NP_ + n) * 224 + m;
#pragma unroll
        for (int g = 0; g < 12; g++) {
            float a = bpost[g];
#pragma unroll
            for (int h = 0; h < 12; h++) a += wpost[g * 12 + h] * e[h];
            P[base + (size_t)g * NP_ * 224] = __float2bfloat16(a);
        }
    }
}

// class-attention: q fp32 [B,C], k/v bf16 [B*197,C] -> o bf16 [B,C]
__global__ __launch_bounds__(256)
void k_ca_attn(const float* __restrict__ q, const bf16* __restrict__ kb,
               const bf16* __restrict__ vb, bf16* __restrict__ o)
{
    __shared__ float sc[200];
    __shared__ float qs[64];
    __shared__ float inv_s;
    int b = blockIdx.x / H_, hh = blockIdx.x % H_;
    int t = threadIdx.x;
    if (t < 64) qs[t] = q[b * C_ + hh * 64 + t] * 0.125f;
    __syncthreads();
    if (t < 197) {
        const bf16* kp = kb + ((size_t)b * 197 + t) * C_ + hh * 64;
        float s = 0.f;
#pragma unroll 8
        for (int d = 0; d < 64; d++) s += qs[d] * b2f(kp[d]);
        sc[t] = s;
    }
    __syncthreads();
    if (t == 0) {
        float mx = -1e30f;
        for (int m = 0; m < 197; m++) mx = fmaxf(mx, sc[m]);
        float sum = 0.f;
        for (int m = 0; m < 197; m++) { float e = expf(sc[m] - mx); sc[m] = e; sum += e; }
        inv_s = 1.0f / sum;
    }
    __syncthreads();
    if (t < 64) {
        const bf16* vp = vb + (size_t)b * 197 * C_ + hh * 64 + t;
        float acc = 0.f;
        for (int m = 0; m < 197; m++) acc += sc[m] * b2f(vp[(size_t)m * C_]);
        o[b * C_ + hh * 64 + t] = __float2bfloat16(acc * inv_s);
    }
}

__global__ __launch_bounds__(256)
void k_bcast_cls(const float* __restrict__ ct, float* __restrict__ cls)
{
    int i = blockIdx.x * 256 + threadIdx.x;              // 12288
    if (i < B_ * C_) cls[i] = ct[i % C_];
}

__global__ __launch_bounds__(256)
void k_zero(float* __restrict__ p, int n)
{
    int i = blockIdx.x * 256 + threadIdx.x;
    if (i < n) p[i] = 0.f;
}

// ---------------------------------------------------------------------------
extern "C" void kernel_launch(void* const* d_in, const int* in_sizes, int n_in,
                              void* d_out, int out_size, void* d_ws, size_t ws_size,
                              hipStream_t stream)
{
    const float* in_x    = (const float*)d_in[0];
    const float* patch_w = (const float*)d_in[1];
    const float* patch_b = (const float*)d_in[2];
    const float* cls_tok = (const float*)d_in[3];
    const float* pos_emb = (const float*)d_in[4];
    const float* n1w = (const float*)d_in[5],  *n1b = (const float*)d_in[6];
    const float* qkvw = (const float*)d_in[7], *qkvb = (const float*)d_in[8];
    const float* plw = (const float*)d_in[9],  *plb = (const float*)d_in[10];
    const float* pww = (const float*)d_in[11], *pwb = (const float*)d_in[12];
    const float* projw = (const float*)d_in[13], *projb = (const float*)d_in[14];
    const float* n2w = (const float*)d_in[15], *n2b = (const float*)d_in[16];
    const float* f1w = (const float*)d_in[17], *f1b = (const float*)d_in[18];
    const float* f2w = (const float*)d_in[19], *f2b = (const float*)d_in[20];
    const float* g1 = (const float*)d_in[21],  *g2 = (const float*)d_in[22];
    const float* tn1w = (const float*)d_in[23], *tn1b = (const float*)d_in[24];
    const float* tqw = (const float*)d_in[25], *tqb = (const float*)d_in[26];
    const float* tkw = (const float*)d_in[27], *tkb = (const float*)d_in[28];
    const float* tvw = (const float*)d_in[29], *tvb = (const float*)d_in[30];
    const float* tprojw = (const float*)d_in[31], *tprojb = (const float*)d_in[32];
    const float* tn2w = (const float*)d_in[33], *tn2b = (const float*)d_in[34];
    const float* tf1w = (const float*)d_in[35], *tf1b = (const float*)d_in[36];
    const float* tf2w = (const float*)d_in[37], *tf2b = (const float*)d_in[38];
    const float* tg1 = (const float*)d_in[39], *tg2 = (const float*)d_in[40];
    const float* normw = (const float*)d_in[41], *normb = (const float*)d_in[42];
    const float* headw = (const float*)d_in[43], *headb = (const float*)d_in[44];
    (void)in_sizes; (void)n_in; (void)out_size; (void)ws_size;

    const int M = B_ * NP_;          // 3136
    char* wsb = (char*)d_ws;
    // ---- workspace layout (bytes) ----
    float* h    = (float*)(wsb + 0);                 //  9,633,792 B fp32 residual
    bf16*  yB   = (bf16*)(wsb + 9633792);            //  4,816,896 B bf16 LN out
    char*  BIG  = wsb + 14450688;                    // 29,503,488 B multi-use
    bf16*  Qb   = (bf16*)(wsb + 43954176);           //  4,816,896
    bf16*  Kb   = (bf16*)(wsb + 48771072);           //  4,816,896
    bf16*  VT   = (bf16*)(wsb + 53587968);           //  5,505,024
    bf16*  P    = (bf16*)(wsb + 59092992);           // 16,859,136
    bf16*  oB   = (bf16*)(wsb + 75952128);           //  4,816,896 -> end 80,769,024
    // BIG aliases (S overlaps qkvB bytes: qkvB must be DEAD before S-GEMM,
    // hence splitqk/splitv copy Q,K,V out first)
    bf16*  pbuf = (bf16*)BIG;                        // patches [3136x768]
    bf16*  qkvB = (bf16*)BIG;                        // [3136x2304] bf16
    float* S    = (float*)BIG;                       // [192][196][196] fp32
    bf16*  hidB = (bf16*)BIG;                        // [3136x3072] bf16
    // class-attention aliases (TH-phase buffers dead)
    bf16*  u    = (bf16*)BIG;                        // [3152x768]
    bf16*  kbuf = (bf16*)(BIG + 5242880);
    bf16*  vbuf = (bf16*)(BIG + 10485760);
    float* qbuf = (float*)(wsb + 43954176);          // 49,152
    bf16*  ca_o = (bf16*)(wsb + 43954176 + 65536);
    bf16*  clsB = (bf16*)(wsb + 43954176 + 262144);
    bf16*  cmlp = (bf16*)(wsb + 43954176 + 327680);
    float* cls  = (float*)(wsb + 59092992);          // alias P (dead in CA phase)

    auto mg = [&](int tm, int tn,
                  const bf16* A, long long sAo, long long sAi, int ABI, int lda,
                  const void* Wt, long long sWo, long long sWi, int WBI, int ldw, int wfp,
                  void* Cc, long long sCo, long long sCi, int CBI, int ldc,
                  const float* bias, const float* resg, int Mm, int Nn, int Kk,
                  float scale, int act, int outbf, int batch, int ksplit, int swz) {
        dim3 g((Nn + tn - 1) / tn, (Mm + tm - 1) / tm, batch * ksplit);
#define MGARGS A, sAo, sAi, ABI, lda, Wt, sWo, sWi, WBI, ldw, (char*)Cc, sCo, sCi, CBI, ldc, \
               bias, resg, Mm, Nn, Kk, scale, act, outbf, ksplit, swz
        if      (tm == 128 && tn == 128 && !wfp) k_mgemm<128,128,2,2,0><<<g,256,0,stream>>>(MGARGS);
        else if (tm ==  64 && tn == 128 &&  wfp) k_mgemm< 64,128,2,2,1><<<g,256,0,stream>>>(MGARGS);
        else if (tm ==  64 && tn ==  64 &&  wfp) k_mgemm< 64, 64,2,2,1><<<g,256,0,stream>>>(MGARGS);
        else if (tm ==  64 && tn ==  64 && !wfp) k_mgemm< 64, 64,2,2,0><<<g,256,0,stream>>>(MGARGS);
#undef MGARGS
    };

    auto sk = [&](const bf16* A, long long lda, const float* Wt, int ldw,
                  void* Cc, int ldc, const float* bias, const float* resg,
                  int Nn, int Kk, int act, int outbf) {
        k_skinny<<<dim3(Nn / 4), 256, 0, stream>>>(A, lda, Wt, ldw, (char*)Cc, ldc,
                                                   bias, resg, Nn, Kk, 1.f, act, outbf);
    };

    // zero P once (tail columns 196..223 must be 0; ws re-poisoned every call)
    k_zero<<<(4214784 + 255) / 256, 256, 0, stream>>>((float*)P, 4214784);

    // ---- patch embed -------------------------------------------------------
    k_patch_gather<<<9408, 256, 0, stream>>>(in_x, pbuf);
    mg(64, 64, pbuf, 0, 0, 1, 768, patch_w, 0, 0, 1, 768, 1, h, 0, 0, 1, 768,
       patch_b, nullptr, M, 768, 768, 1.f, 0, 0, 1, 1, 1);
    k_addpos<<<9408, 256, 0, stream>>>(h, pos_emb);

    // ---- 12 talking-heads blocks ------------------------------------------
    for (int L = 0; L < 12; L++) {
        size_t lC = (size_t)L * C_;
        k_ln<<<M, 256, 0, stream>>>(h, n1w + lC, n1b + lC, yB);
        mg(64, 128, yB, 0, 0, 1, 768, qkvw + (size_t)L * 2304 * 768, 0, 0, 1, 768, 1,
           qkvB, 0, 0, 1, 2304, qkvb + (size_t)L * 2304, nullptr,
           M, 2304, 768, 1.f, 0, 1, 1, 1, 1);
        k_splitqk<<<9408, 256, 0, stream>>>(qkvB, Qb, Kb);
        k_splitv<<<10752, 256, 0, stream>>>(qkvB, VT);
        // S[z] = 0.125 * Qb[z] @ Kb[z]^T  (qkvB now dead; S may clobber it)
        mg(128, 128, Qb, 12544, 0, 1, 64, Kb, 12544, 0, 1, 64, 0,
           S, NPNP, 0, 1, 196, nullptr, nullptr,
           196, 196, 64, 0.125f, 0, 0, 192, 1, 0);
        // fused pre-mix + softmax + post-mix -> P bf16 [z][196][224]
        k_attn_mix<<<M, 256, 0, stream>>>(S, plw + L * 144, plb + L * 12,
                                          pww + L * 144, pwb + L * 12, P);
        // o[b][n][h*64+d] = P[z] @ V[z]  (K=224 zero-padded)
        mg(64, 64, P, 43904, 0, 1, 224, VT, 14336, 0, 1, 224, 0,
           oB, 150528, 64, H_, 768, nullptr, nullptr,
           196, 64, 224, 1.f, 0, 1, 192, 1, 0);
        // proj with fused residual: h += g1 * (oB @ projw^T + projb)
        mg(64, 64, oB, 0, 0, 1, 768, projw + (size_t)L * 768 * 768, 0, 0, 1, 768, 1,
           h, 0, 0, 1, 768, projb + lC, g1 + lC, M, 768, 768, 1.f, 0, 0, 1, 1, 1);
        k_ln<<<M, 256, 0, stream>>>(h, n2w + lC, n2b + lC, yB);
        mg(64, 128, yB, 0, 0, 1, 768, f1w + (size_t)L * 3072 * 768, 0, 0, 1, 768, 1,
           hidB, 0, 0, 1, 3072, f1b + (size_t)L * 3072, nullptr,
           M, 3072, 768, 1.f, 1, 1, 1, 1, 1);
        // f2 with fused residual (K-split 2, atomic): h += g2 * (hidB @ f2w^T + f2b)
        mg(64, 64, hidB, 0, 0, 1, 3072, f2w + (size_t)L * 768 * 3072, 0, 0, 1, 3072, 1,
           h, 0, 0, 1, 768, f2b + lC, g2 + lC, M, 768, 3072, 1.f, 0, 0, 1, 2, 1);
    }

    // ---- 2 class-attention blocks -----------------------------------------
    k_bcast_cls<<<48, 256, 0, stream>>>(cls_tok, cls);
    const int Mu = B_ * 197;         // 3152
    for (int t = 0; t < 2; t++) {
        size_t tC = (size_t)t * C_;
        size_t tCC = (size_t)t * 768 * 768;
        size_t tFC = (size_t)t * 3072 * 768;
        k_ln_cat<<<Mu, 256, 0, stream>>>(cls, h, tn1w + tC, tn1b + tC, u);
        sk(u, 197 * 768, tqw + tCC, 768, qbuf, 768, tqb + tC, nullptr, 768, 768, 0, 0);
        mg(64, 64, u, 0, 0, 1, 768, tkw + tCC, 0, 0, 1, 768, 1,
           kbuf, 0, 0, 1, 768, tkb + tC, nullptr, Mu, 768, 768, 1.f, 0, 1, 1, 1, 1);
        mg(64, 64, u, 0, 0, 1, 768, tvw + tCC, 0, 0, 1, 768, 1,
           vbuf, 0, 0, 1, 768, tvb + tC, nullptr, Mu, 768, 768, 1.f, 0, 1, 1, 1, 1);
        k_ca_attn<<<B_ * H_, 256, 0, stream>>>(qbuf, kbuf, vbuf, ca_o);
        // cls += tg1 * (ca_o @ tprojw^T + tprojb)
        sk(ca_o, 768, tprojw + tCC, 768, cls, 768, tprojb + tC, tg1 + tC, 768, 768, 0, 0);
        k_ln<<<B_, 256, 0, stream>>>(cls, tn2w + tC, tn2b + tC, clsB);
        sk(clsB, 768, tf1w + tFC, 768, cmlp, 3072, tf1b + (size_t)t * 3072, nullptr,
           3072, 768, 1, 1);
        // cls += tg2 * (cmlp @ tf2w^T + tf2b)
        sk(cmlp, 3072, tf2w + tFC, 3072, cls, 768, tf2b + tC, tg2 + tC, 768, 3072, 0, 0);
    }

    // ---- final LN (cls only) + head directly to d_out (fp32) --------------
    k_ln<<<B_, 256, 0, stream>>>(cls, normw, normb, clsB);
    sk(clsB, 768, headw, 768, d_out, 1000, headb, nullptr, 1000, 768, 0, 0);
}